// Round 2
// baseline (212.830 us; speedup 1.0000x reference)
//
#include <hip/hip_runtime.h>
#include <hip/hip_bf16.h>
#include <stdint.h>

// Problem constants (B,T,C fixed by setup_inputs)
#define B_SZ   8
#define T_SEQ  2048
#define C_DIM  1024
#define NH     16
#define HS     64
#define M_DIM  (B_SZ * T_SEQ)   // 16384 rows of the GEMM
#define EXP_SC 10.0f
#define KS_MAX 11.090339630053288f   // log(2^16 - 1)

typedef _Float16 f16;
typedef __attribute__((ext_vector_type(8))) _Float16 f16x8;
typedef __attribute__((ext_vector_type(4))) float f32x4;

// ---------------------------------------------------------------- f16 cast
__global__ void cast_f32_to_f16(const float* __restrict__ in,
                                f16* __restrict__ out, int n8) {
  int stride = gridDim.x * blockDim.x;
  for (int i = blockIdx.x * blockDim.x + threadIdx.x; i < n8; i += stride) {
    const float* p = in + (size_t)i * 8;
    float4 a = *(const float4*)p;
    float4 b = *(const float4*)(p + 4);
    f16x8 o;
    o[0] = (f16)a.x; o[1] = (f16)a.y; o[2] = (f16)a.z; o[3] = (f16)a.w;
    o[4] = (f16)b.x; o[5] = (f16)b.y; o[6] = (f16)b.z; o[7] = (f16)b.w;
    *(f16x8*)(out + (size_t)i * 8) = o;
  }
}

// --------------------------------------------------- async global->LDS copy
// low 32 bits of a generic LDS pointer are the LDS offset on gfx9+.
__device__ __forceinline__ void gl_lds16(const f16* g, const f16* l) {
  __builtin_amdgcn_global_load_lds(
      (const __attribute__((address_space(1))) void*)(uintptr_t)(const void*)g,
      (__attribute__((address_space(3))) void*)(uintptr_t)(const void*)l,
      16, 0, 0);
}

// ------------------------------------------------------------- f16 GEMM
// C[m,n] = sum_k A[m,k] * Bt[n,k]   (A: M x K row-major, Bt: N x K row-major)
// m97 structure: 128x128 tile, BK=32, 256 threads (4 waves, 2x2), 16x16x32 MFMA.
__global__ __launch_bounds__(256, 2)
void gemm_bt_f16(const f16* __restrict__ A,
                 const f16* __restrict__ Bt,
                 float* __restrict__ C) {
  __shared__ f16 As[128 * 32];
  __shared__ f16 Bs[128 * 32];

  const int tid = threadIdx.x;
  const int w = tid >> 6, l = tid & 63;
  const int bn = blockIdx.x & 7;        // N/128 = 8 (fastest -> A-panel L2/L3 reuse)
  const int bm = blockIdx.x >> 3;       // M/128 = 128
  const int wm = w >> 1, wn = w & 1;    // each wave owns a 64x64 sub-tile

  const f32x4 zero = {0.f, 0.f, 0.f, 0.f};
  f32x4 acc[4][4];
#pragma unroll
  for (int i = 0; i < 4; ++i)
#pragma unroll
    for (int j = 0; j < 4; ++j) acc[i][j] = zero;

  const f16* Ag = A + (size_t)(bm * 128) * C_DIM;
  const f16* Bg = Bt + (size_t)(bn * 128) * C_DIM;

  // fragment read coords (16x16x32: lane holds 8 contiguous k at row l&15)
  const int fr = l & 15;
  const int fk = l >> 4;                // 0..3 -> k offset fk*8

  for (int k0 = 0; k0 < C_DIM; k0 += 32) {
    __syncthreads();
    // stage 8KB A + 8KB B: chunk q = call*256 + w*64 + l, 16B per chunk.
    // LDS linear: chunk q -> row q>>2, col8 = (q&3)*8  (matches global src)
#pragma unroll
    for (int call = 0; call < 2; ++call) {
      int q = call * 256 + w * 64 + l;
      int r = q >> 2, c8 = (q & 3) << 3;
      const f16* ga = Ag + (size_t)r * C_DIM + k0 + c8;
      const f16* gb = Bg + (size_t)r * C_DIM + k0 + c8;
      const f16* la = As + (size_t)(call * 256 + w * 64) * 8;  // wave-uniform base
      const f16* lb = Bs + (size_t)(call * 256 + w * 64) * 8;
      gl_lds16(ga, la);
      gl_lds16(gb, lb);
    }
    __syncthreads();   // compiler drains vmcnt before barrier

    f16x8 af[4], bfr[4];
#pragma unroll
    for (int i = 0; i < 4; ++i)
      af[i] = *(const f16x8*)(As + (wm * 64 + i * 16 + fr) * 32 + fk * 8);
#pragma unroll
    for (int j = 0; j < 4; ++j)
      bfr[j] = *(const f16x8*)(Bs + (wn * 64 + j * 16 + fr) * 32 + fk * 8);
#pragma unroll
    for (int i = 0; i < 4; ++i)
#pragma unroll
      for (int j = 0; j < 4; ++j)
        acc[i][j] = __builtin_amdgcn_mfma_f32_16x16x32_f16(af[i], bfr[j],
                                                           acc[i][j], 0, 0, 0);
  }

  // epilogue: C/D layout col = lane&15, row = (lane>>4)*4 + reg  [m89-verified]
  const int orow0 = bm * 128 + wm * 64 + (l >> 4) * 4;
  const int ocol0 = bn * 128 + wn * 64 + (l & 15);
#pragma unroll
  for (int i = 0; i < 4; ++i)
#pragma unroll
    for (int j = 0; j < 4; ++j)
#pragma unroll
      for (int r = 0; r < 4; ++r)
        C[(size_t)(orow0 + i * 16 + r) * C_DIM + ocol0 + j * 16] = acc[i][j][r];
}

// -------------------------------------------- fused leaky-scan + L2-norm + scale
// y[t] = e^{-beta_h} * y[t-1] + k[t] ; out = y/(||y||_2 + 1e-10) * scale_h
// One wave per (b, h, 64-t chunk); lane = head-dim d. 64-step lookback:
// truncation <= exp(-0.5*64) ~ 1.3e-14 << f32 eps  (beta_min = 0.5).
__global__ __launch_bounds__(256)
void scan_norm(const float* __restrict__ kbuf,      // (B*T, C) f32
               const float* __restrict__ beta_p,    // 16
               const float* __restrict__ ks_p,      // 16
               const int* __restrict__ sp_p,        // 1
               float* __restrict__ out) {           // (B, NH, T, HS)
  const int l = threadIdx.x & 63;
  const int gw = blockIdx.x * 4 + (threadIdx.x >> 6);  // 4096 waves total
  const int c = gw & 31;          // T/64 = 32 chunks
  const int h = (gw >> 5) & 15;
  const int b = gw >> 9;

  const float beta = fabsf(beta_p[h]) * EXP_SC;
  const float a = expf(-beta);
  const float sp = (float)sp_p[0];
  const float scale = expf(fminf(sp * EXP_SC * ks_p[h], KS_MAX));

  const float* kp = kbuf + (size_t)b * T_SEQ * C_DIM + h * HS + l;
  float* op = out + ((size_t)(b * NH + h) * T_SEQ) * HS + l;

  const int t0 = c * 64;
  float y = 0.f;
  // lookback warm-up (none for chunk 0 -> exact there)
  int s = (t0 >= 64) ? (t0 - 64) : 0;
#pragma unroll 8
  for (; s < t0; ++s)
    y = fmaf(a, y, kp[(size_t)s * C_DIM]);

#pragma unroll 4
  for (int t = t0; t < t0 + 64; ++t) {
    y = fmaf(a, y, kp[(size_t)t * C_DIM]);
    float sq = y * y;
#pragma unroll
    for (int m = 1; m < 64; m <<= 1)
      sq += __shfl_xor(sq, m, 64);
    float nrm = sqrtf(sq) + 1e-10f;
    op[(size_t)t * HS] = y * (scale / nrm);
  }
}

// --------------------------------------------------------------- launcher
extern "C" void kernel_launch(void* const* d_in, const int* in_sizes, int n_in,
                              void* d_out, int out_size, void* d_ws, size_t ws_size,
                              hipStream_t stream) {
  const float* x      = (const float*)d_in[0];   // (8,2048,1024) f32
  const float* Wk     = (const float*)d_in[1];   // (1024,1024) f32
  const float* beta   = (const float*)d_in[2];   // (16) f32
  const float* kscale = (const float*)d_in[3];   // (16) f32
  const int*   spow   = (const int*)d_in[4];     // (1) int
  float* out = (float*)d_out;

  // workspace layout: x_f16 (32MB) | W_f16 (2MB) | k_f32 (64MB)  ~= 98MB
  f16* x_h = (f16*)d_ws;
  f16* W_h = x_h + (size_t)M_DIM * C_DIM;
  float* kbuf = (float*)(W_h + (size_t)C_DIM * C_DIM);

  cast_f32_to_f16<<<2048, 256, 0, stream>>>(x, x_h, (M_DIM * C_DIM) / 8);
  cast_f32_to_f16<<<512, 256, 0, stream>>>(Wk, W_h, (C_DIM * C_DIM) / 8);
  gemm_bt_f16<<<dim3((M_DIM / 128) * (C_DIM / 128)), 256, 0, stream>>>(x_h, W_h, kbuf);
  scan_norm<<<1024, 256, 0, stream>>>(kbuf, beta, kscale, spow, out);
}

// Round 4
// 205.225 us; speedup vs baseline: 1.0371x; 1.0371x over previous
//
#include <hip/hip_runtime.h>
#include <hip/hip_bf16.h>
#include <stdint.h>

// Problem constants (B,T,C fixed by setup_inputs)
#define B_SZ   8
#define T_SEQ  2048
#define C_DIM  1024
#define NH     16
#define HS     64
#define M_DIM  (B_SZ * T_SEQ)   // 16384 rows of the GEMM
#define EXP_SC 10.0f
#define KS_MAX 11.090339630053288f   // log(2^16 - 1)

typedef _Float16 f16;
typedef __attribute__((ext_vector_type(8))) _Float16 f16x8;
typedef __attribute__((ext_vector_type(4))) float f32x4;

// ---------------------------------------------------------------- f16 cast
// single dispatch handles both x (64MB) and Wk (4MB)
__global__ void cast_two(const float* __restrict__ xin, f16* __restrict__ xout, int n8x,
                         const float* __restrict__ win, f16* __restrict__ wout, int n8w) {
  int stride = gridDim.x * blockDim.x;
  int t0 = blockIdx.x * blockDim.x + threadIdx.x;
  for (int i = t0; i < n8x; i += stride) {
    const float* p = xin + (size_t)i * 8;
    float4 a = *(const float4*)p;
    float4 b = *(const float4*)(p + 4);
    f16x8 o;
    o[0] = (f16)a.x; o[1] = (f16)a.y; o[2] = (f16)a.z; o[3] = (f16)a.w;
    o[4] = (f16)b.x; o[5] = (f16)b.y; o[6] = (f16)b.z; o[7] = (f16)b.w;
    *(f16x8*)(xout + (size_t)i * 8) = o;
  }
  for (int i = t0; i < n8w; i += stride) {
    const float* p = win + (size_t)i * 8;
    float4 a = *(const float4*)p;
    float4 b = *(const float4*)(p + 4);
    f16x8 o;
    o[0] = (f16)a.x; o[1] = (f16)a.y; o[2] = (f16)a.z; o[3] = (f16)a.w;
    o[4] = (f16)b.x; o[5] = (f16)b.y; o[6] = (f16)b.z; o[7] = (f16)b.w;
    *(f16x8*)(wout + (size_t)i * 8) = o;
  }
}

// --------------------------------------------------- async global->LDS copy
// low 32 bits of a generic LDS pointer are the LDS offset on gfx9+.
__device__ __forceinline__ void gl_lds16(const f16* g, const f16* l) {
  __builtin_amdgcn_global_load_lds(
      (const __attribute__((address_space(1))) void*)(uintptr_t)(const void*)g,
      (__attribute__((address_space(3))) void*)(uintptr_t)(const void*)l,
      16, 0, 0);
}

// ------------------------------------------------------------- f16 GEMM
// C[m,n] = sum_k A[m,k] * Bt[n,k]   (A: M x K row-major, Bt: N x K row-major)
// 128x128 tile, BK=32, 256 threads (4 waves, 2x2), 16x16x32 MFMA.
//  + XCD-bijective block swizzle (A-panel L2 reuse; FETCH 133MB -> ~55MB pred)
//  + LDS double-buffer, single-barrier 2-phase K-loop (T3 minimum recipe)
__global__ __launch_bounds__(256, 2)
void gemm_bt_f16(const f16* __restrict__ A,
                 const f16* __restrict__ Bt,
                 float* __restrict__ C) {
  __shared__ f16 As[2][128 * 32];
  __shared__ f16 Bs[2][128 * 32];

  const int tid = threadIdx.x;
  const int w = tid >> 6, l = tid & 63;

  // m204 bijective XCD swizzle (nwg=1024, 8 XCDs): XCD x owns wgid in
  // [x*128, (x+1)*128) -> bm in [x*16, x*16+16): 16 A-panels (4MB) + W (2MB)
  // per-XCD working set ~ L2-fit. Consecutive blocks on an XCD share bm.
  const int q = blockIdx.x;
  const int wgid = (q & 7) * 128 + (q >> 3);
  const int bm = wgid >> 3;            // 0..127
  const int bn = wgid & 7;             // 0..7

  const int wm = w >> 1, wn = w & 1;   // each wave owns a 64x64 sub-tile

  const f32x4 zero = {0.f, 0.f, 0.f, 0.f};
  f32x4 acc[4][4];
#pragma unroll
  for (int i = 0; i < 4; ++i)
#pragma unroll
    for (int j = 0; j < 4; ++j) acc[i][j] = zero;

  const f16* Ag = A + (size_t)(bm * 128) * C_DIM;
  const f16* Bg = Bt + (size_t)(bn * 128) * C_DIM;

  // staging: chunk qc = call*256 + w*64 + l, 16B each; LDS linear
  // (row = qc>>2, col8 = (qc&3)*8 matches global source layout)
  const int r0  = (w * 64 + l) >> 2;          // call 0 row
  const int c8  = ((w * 64 + l) & 3) << 3;    // col offset (same both calls)
  const int lo0 = (w * 64 + l) * 8;           // LDS elem offset, call 0
  // call 1 adds 256 chunks = 64 rows / 2048 elems

  // fragment read coords (16x16x32: lane holds 8 contiguous k at row l&15)
  const int fr = l & 15;
  const int fk = l >> 4;               // 0..3 -> k offset fk*8

#define STAGE(buf, k0)                                                   \
  do {                                                                   \
    gl_lds16(Ag + (size_t)r0 * C_DIM + (k0) + c8,        As[buf] + lo0); \
    gl_lds16(Bg + (size_t)r0 * C_DIM + (k0) + c8,        Bs[buf] + lo0); \
    gl_lds16(Ag + (size_t)(r0 + 64) * C_DIM + (k0) + c8, As[buf] + lo0 + 2048); \
    gl_lds16(Bg + (size_t)(r0 + 64) * C_DIM + (k0) + c8, Bs[buf] + lo0 + 2048); \
  } while (0)

  STAGE(0, 0);
  __syncthreads();                     // drains vmcnt -> buf0 ready

  int cur = 0;
  for (int step = 0; step < 32; ++step) {
    if (step + 1 < 32) STAGE(cur ^ 1, (step + 1) * 32);  // prefetch next tile

    f16x8 af[4], bfr[4];
#pragma unroll
    for (int i = 0; i < 4; ++i)
      af[i] = *(const f16x8*)(As[cur] + (wm * 64 + i * 16 + fr) * 32 + fk * 8);
#pragma unroll
    for (int j = 0; j < 4; ++j)
      bfr[j] = *(const f16x8*)(Bs[cur] + (wn * 64 + j * 16 + fr) * 32 + fk * 8);
#pragma unroll
    for (int i = 0; i < 4; ++i)
#pragma unroll
      for (int j = 0; j < 4; ++j)
        acc[i][j] = __builtin_amdgcn_mfma_f32_16x16x32_f16(af[i], bfr[j],
                                                           acc[i][j], 0, 0, 0);

    __syncthreads();   // one barrier/step: drains prefetch vmcnt + lds reads
    cur ^= 1;
  }
#undef STAGE

  // epilogue: C/D layout col = lane&15, row = (lane>>4)*4 + reg  [m89-verified]
  const int orow0 = bm * 128 + wm * 64 + (l >> 4) * 4;
  const int ocol0 = bn * 128 + wn * 64 + (l & 15);
#pragma unroll
  for (int i = 0; i < 4; ++i)
#pragma unroll
    for (int j = 0; j < 4; ++j)
#pragma unroll
      for (int r = 0; r < 4; ++r)
        C[(size_t)(orow0 + i * 16 + r) * C_DIM + ocol0 + j * 16] = acc[i][j][r];
}

// -------------------------------------------- fused leaky-scan + L2-norm + scale
// y[t] = e^{-beta_h} * y[t-1] + k[t] ; out = y/(||y||_2 + 1e-10) * scale_h
// One wave per (b, h, 64-t chunk); lane = head-dim d. 64-step lookback:
// truncation <= exp(-0.5*64) ~ 1.3e-14 << f32 eps  (beta_min = 0.5).
__global__ __launch_bounds__(256)
void scan_norm(const float* __restrict__ kbuf,      // (B*T, C) f32
               const float* __restrict__ beta_p,    // 16
               const float* __restrict__ ks_p,      // 16
               const int* __restrict__ sp_p,        // 1
               float* __restrict__ out) {           // (B, NH, T, HS)
  const int l = threadIdx.x & 63;
  const int gw = blockIdx.x * 4 + (threadIdx.x >> 6);  // 4096 waves total
  const int c = gw & 31;          // T/64 = 32 chunks
  const int h = (gw >> 5) & 15;
  const int b = gw >> 9;

  const float beta = fabsf(beta_p[h]) * EXP_SC;
  const float a = expf(-beta);
  const float sp = (float)sp_p[0];
  const float scale = expf(fminf(sp * EXP_SC * ks_p[h], KS_MAX));

  const float* kp = kbuf + (size_t)b * T_SEQ * C_DIM + h * HS + l;
  float* op = out + ((size_t)(b * NH + h) * T_SEQ) * HS + l;

  const int t0 = c * 64;
  float y = 0.f;
  // lookback warm-up (none for chunk 0 -> exact there)
  int s = (t0 >= 64) ? (t0 - 64) : 0;
#pragma unroll 8
  for (; s < t0; ++s)
    y = fmaf(a, y, kp[(size_t)s * C_DIM]);

#pragma unroll 4
  for (int t = t0; t < t0 + 64; ++t) {
    y = fmaf(a, y, kp[(size_t)t * C_DIM]);
    float sq = y * y;
#pragma unroll
    for (int m = 1; m < 64; m <<= 1)
      sq += __shfl_xor(sq, m, 64);
    float nrm = sqrtf(sq) + 1e-10f;
    op[(size_t)t * HS] = y * (scale / nrm);
  }
}

// --------------------------------------------------------------- launcher
extern "C" void kernel_launch(void* const* d_in, const int* in_sizes, int n_in,
                              void* d_out, int out_size, void* d_ws, size_t ws_size,
                              hipStream_t stream) {
  const float* x      = (const float*)d_in[0];   // (8,2048,1024) f32
  const float* Wk     = (const float*)d_in[1];   // (1024,1024) f32
  const float* beta   = (const float*)d_in[2];   // (16) f32
  const float* kscale = (const float*)d_in[3];   // (16) f32
  const int*   spow   = (const int*)d_in[4];     // (1) int
  float* out = (float*)d_out;

  // workspace layout: x_f16 (32MB) | W_f16 (2MB) | k_f32 (64MB)  ~= 98MB
  f16* x_h = (f16*)d_ws;
  f16* W_h = x_h + (size_t)M_DIM * C_DIM;
  float* kbuf = (float*)(W_h + (size_t)C_DIM * C_DIM);

  cast_two<<<2048, 256, 0, stream>>>(x, x_h, (M_DIM * C_DIM) / 8,
                                     Wk, W_h, (C_DIM * C_DIM) / 8);
  gemm_bt_f16<<<dim3((M_DIM / 128) * (C_DIM / 128)), 256, 0, stream>>>(x_h, W_h, kbuf);
  scan_norm<<<1024, 256, 0, stream>>>(kbuf, beta, kscale, spow, out);
}

// Round 6
// 198.235 us; speedup vs baseline: 1.0736x; 1.0353x over previous
//
#include <hip/hip_runtime.h>
#include <hip/hip_bf16.h>
#include <stdint.h>

// Problem constants (B,T,C fixed by setup_inputs)
#define B_SZ   8
#define T_SEQ  2048
#define C_DIM  1024
#define NH     16
#define HS     64
#define M_DIM  (B_SZ * T_SEQ)   // 16384 rows of the GEMM
#define EXP_SC 10.0f
#define KS_MAX 11.090339630053288f   // log(2^16 - 1)

typedef _Float16 f16;
typedef __attribute__((ext_vector_type(8))) _Float16 f16x8;
typedef __attribute__((ext_vector_type(4))) float f32x4;

// ---------------------------------------------------------------- f16 cast
__global__ void cast_two(const float* __restrict__ xin, f16* __restrict__ xout, int n8x,
                         const float* __restrict__ win, f16* __restrict__ wout, int n8w) {
  int stride = gridDim.x * blockDim.x;
  int t0 = blockIdx.x * blockDim.x + threadIdx.x;
  for (int i = t0; i < n8x; i += stride) {
    const float* p = xin + (size_t)i * 8;
    float4 a = *(const float4*)p;
    float4 b = *(const float4*)(p + 4);
    f16x8 o;
    o[0] = (f16)a.x; o[1] = (f16)a.y; o[2] = (f16)a.z; o[3] = (f16)a.w;
    o[4] = (f16)b.x; o[5] = (f16)b.y; o[6] = (f16)b.z; o[7] = (f16)b.w;
    *(f16x8*)(xout + (size_t)i * 8) = o;
  }
  for (int i = t0; i < n8w; i += stride) {
    const float* p = win + (size_t)i * 8;
    float4 a = *(const float4*)p;
    float4 b = *(const float4*)(p + 4);
    f16x8 o;
    o[0] = (f16)a.x; o[1] = (f16)a.y; o[2] = (f16)a.z; o[3] = (f16)a.w;
    o[4] = (f16)b.x; o[5] = (f16)b.y; o[6] = (f16)b.z; o[7] = (f16)b.w;
    *(f16x8*)(wout + (size_t)i * 8) = o;
  }
}

// --------------------------------------------------- async global->LDS copy
__device__ __forceinline__ void gl_lds16(const f16* g, const f16* l) {
  __builtin_amdgcn_global_load_lds(
      (const __attribute__((address_space(1))) void*)(uintptr_t)(const void*)g,
      (__attribute__((address_space(3))) void*)(uintptr_t)(const void*)l,
      16, 0, 0);
}

// ------------------------------------------------------------- f16 GEMM, 8-phase
// C[m,n] = sum_k A[m,k]*Bt[n,k].  256x256 tile, BK=64, 512 threads (8 waves 2Mx4N),
// per-wave C 128x64 = acc[8][4] f32x4.  4 quadrant-phases per K-tile:
//   {ds_read frags, stage issue, s_barrier, lgkmcnt(0), setprio(1), 16 MFMA,
//    setprio(0), s_barrier};  vmcnt(0) only at phase 4 (loads fly over 3 phases).
// LDS swizzle: source-side XOR (rule #21): lane l stages G[row][slot^(row&7)]
// into linear LDS[row][slot]; reader reads LDS[row][slot^(row&7)] -> G[row][slot].
__global__ __launch_bounds__(512, 2)
void gemm_bt_f16_8p(const f16* __restrict__ A,
                    const f16* __restrict__ Bt,
                    float* __restrict__ C) {
  __shared__ f16 As[2][2][128 * 64];   // [dbuf][M-half][128 rows x 64 cols]
  __shared__ f16 Bs[2][2][128 * 64];   // [dbuf][N-half][...]           128KB total

  const int tid = threadIdx.x;
  const int w = tid >> 6, l = tid & 63;
  const int wm = w >> 2, wn = w & 3;          // 2M x 4N waves

  // XCD-bijective swizzle: nwg=256, 8 XCDs -> 32 contiguous wgids each
  const int q = blockIdx.x;
  const int wgid = (q & 7) * 32 + (q >> 3);
  const int bm = wgid >> 2;                   // 0..63
  const int bn = wgid & 3;                    // 0..3

  // ---- staging per-lane constants (pre-swizzled global source)
  const int srow = l >> 3;                    // row within 8-row group == row&7
  const int sswz = (((l & 7) ^ srow)) << 3;   // swizzled col (elems)
  const size_t a_lane = (size_t)(bm * 256 + w * 8 + srow) * C_DIM + sswz;
  const size_t b_lane = (size_t)(bn * 256 + w * 8 + srow) * C_DIM + sswz;
  const int lds_w = w * 512;                  // wave slice inside one call block

  // ---- fragment per-lane constants (swizzled LDS read)
  const int fr = l & 15;
  const int fk = l >> 4;                      // k-slot within 32
  const int ck0 = ((fk) ^ (l & 7)) << 3;      // kk=0 col (elems)
  const int ck1 = ((4 + fk) ^ (l & 7)) << 3;  // kk=1 col

  const f32x4 zero = {0.f, 0.f, 0.f, 0.f};
  f32x4 acc[8][4];
#pragma unroll
  for (int i = 0; i < 8; ++i)
#pragma unroll
    for (int j = 0; j < 4; ++j) acc[i][j] = zero;

  f16x8 af[4][2], b0[2][2], b1[2][2];

#define STAGE_A(buf, kt) do {                                                \
    size_t ko = (size_t)(kt) * 64;                                           \
    gl_lds16(A + a_lane + ko,                         &As[buf][0][lds_w]);        \
    gl_lds16(A + a_lane + ko + (size_t) 64 * C_DIM,   &As[buf][0][lds_w + 4096]); \
    gl_lds16(A + a_lane + ko + (size_t)128 * C_DIM,   &As[buf][1][lds_w]);        \
    gl_lds16(A + a_lane + ko + (size_t)192 * C_DIM,   &As[buf][1][lds_w + 4096]); \
  } while (0)
#define STAGE_B(buf, kt) do {                                                \
    size_t ko = (size_t)(kt) * 64;                                           \
    gl_lds16(Bt + b_lane + ko,                        &Bs[buf][0][lds_w]);        \
    gl_lds16(Bt + b_lane + ko + (size_t) 64 * C_DIM,  &Bs[buf][0][lds_w + 4096]); \
    gl_lds16(Bt + b_lane + ko + (size_t)128 * C_DIM,  &Bs[buf][1][lds_w]);        \
    gl_lds16(Bt + b_lane + ko + (size_t)192 * C_DIM,  &Bs[buf][1][lds_w + 4096]); \
  } while (0)

#define MFMA16(mi, ni, BREG) do {                                            \
    _Pragma("unroll") for (int kk = 0; kk < 2; ++kk)                         \
    _Pragma("unroll") for (int i = 0; i < 4; ++i)                            \
    _Pragma("unroll") for (int j = 0; j < 2; ++j)                            \
      acc[(mi)*4 + i][(ni)*2 + j] = __builtin_amdgcn_mfma_f32_16x16x32_f16(  \
          af[i][kk], BREG[j][kk], acc[(mi)*4 + i][(ni)*2 + j], 0, 0, 0);     \
  } while (0)

  // prologue: stage K-tile 0 into buf 0
  STAGE_A(0, 0); STAGE_B(0, 0);
  __syncthreads();                     // drains vmcnt -> buf0 ready

  for (int kt = 0; kt < 16; ++kt) {
    const int cur = kt & 1;
    const f16* Ab = &As[cur][wm][0];
    const f16* Bb = &Bs[cur][wn >> 1][(wn & 1) * 4096];

    // ---- phase 1: Q(mi=0, ni=0)  [12 ds_reads + A-stage issue]
#pragma unroll
    for (int i = 0; i < 4; ++i) {
      af[i][0] = *(const f16x8*)(Ab + (i * 16 + fr) * 64 + ck0);
      af[i][1] = *(const f16x8*)(Ab + (i * 16 + fr) * 64 + ck1);
    }
#pragma unroll
    for (int j = 0; j < 2; ++j) {
      b0[j][0] = *(const f16x8*)(Bb + (j * 16 + fr) * 64 + ck0);
      b0[j][1] = *(const f16x8*)(Bb + (j * 16 + fr) * 64 + ck1);
    }
    if (kt < 15) STAGE_A(cur ^ 1, kt + 1);
    __builtin_amdgcn_s_barrier();
    asm volatile("s_waitcnt lgkmcnt(0)" ::: "memory");
    __builtin_amdgcn_s_setprio(1);
    MFMA16(0, 0, b0);
    __builtin_amdgcn_s_setprio(0);
    __builtin_amdgcn_s_barrier();

    // ---- phase 2: Q(0,1)  [4 ds_reads + B-stage issue]
#pragma unroll
    for (int j = 0; j < 2; ++j) {
      b1[j][0] = *(const f16x8*)(Bb + ((2 + j) * 16 + fr) * 64 + ck0);
      b1[j][1] = *(const f16x8*)(Bb + ((2 + j) * 16 + fr) * 64 + ck1);
    }
    if (kt < 15) STAGE_B(cur ^ 1, kt + 1);
    __builtin_amdgcn_s_barrier();
    asm volatile("s_waitcnt lgkmcnt(0)" ::: "memory");
    __builtin_amdgcn_s_setprio(1);
    MFMA16(0, 1, b1);
    __builtin_amdgcn_s_setprio(0);
    __builtin_amdgcn_s_barrier();

    // ---- phase 3: Q(1,1)  [8 ds_reads: A rows 64..127]
#pragma unroll
    for (int i = 0; i < 4; ++i) {
      af[i][0] = *(const f16x8*)(Ab + (64 + i * 16 + fr) * 64 + ck0);
      af[i][1] = *(const f16x8*)(Ab + (64 + i * 16 + fr) * 64 + ck1);
    }
    __builtin_amdgcn_s_barrier();
    asm volatile("s_waitcnt lgkmcnt(0)" ::: "memory");
    __builtin_amdgcn_s_setprio(1);
    MFMA16(1, 1, b1);
    __builtin_amdgcn_s_setprio(0);
    __builtin_amdgcn_s_barrier();

    // ---- phase 4: Q(1,0)  [no ds_reads; b0 still live]
    __builtin_amdgcn_s_setprio(1);
    MFMA16(1, 0, b0);
    __builtin_amdgcn_s_setprio(0);
    asm volatile("s_waitcnt vmcnt(0)" ::: "memory");  // kt+1 stages landed
    __builtin_amdgcn_s_barrier();
  }
#undef STAGE_A
#undef STAGE_B
#undef MFMA16

  // epilogue: C/D layout col = lane&15, row = (lane>>4)*4 + reg  [m89-verified]
  const int orow0 = bm * 256 + wm * 128 + (l >> 4) * 4;
  const int ocol0 = bn * 256 + wn * 64 + (l & 15);
#pragma unroll
  for (int i = 0; i < 8; ++i)
#pragma unroll
    for (int j = 0; j < 4; ++j)
#pragma unroll
      for (int r = 0; r < 4; ++r)
        C[(size_t)(orow0 + i * 16 + r) * C_DIM + ocol0 + j * 16] = acc[i][j][r];
}

// -------------------------------------------- fused leaky-scan + L2-norm + scale
__global__ __launch_bounds__(256)
void scan_norm(const float* __restrict__ kbuf,      // (B*T, C) f32
               const float* __restrict__ beta_p,    // 16
               const float* __restrict__ ks_p,      // 16
               const int* __restrict__ sp_p,        // 1
               float* __restrict__ out) {           // (B, NH, T, HS)
  const int l = threadIdx.x & 63;
  const int gw = blockIdx.x * 4 + (threadIdx.x >> 6);  // 4096 waves total
  const int c = gw & 31;          // T/64 = 32 chunks
  const int h = (gw >> 5) & 15;
  const int b = gw >> 9;

  const float beta = fabsf(beta_p[h]) * EXP_SC;
  const float a = expf(-beta);
  const float sp = (float)sp_p[0];
  const float scale = expf(fminf(sp * EXP_SC * ks_p[h], KS_MAX));

  const float* kp = kbuf + (size_t)b * T_SEQ * C_DIM + h * HS + l;
  float* op = out + ((size_t)(b * NH + h) * T_SEQ) * HS + l;

  const int t0 = c * 64;
  float y = 0.f;
  int s = (t0 >= 64) ? (t0 - 64) : 0;   // 64-step lookback: trunc ~1.3e-14
#pragma unroll 8
  for (; s < t0; ++s)
    y = fmaf(a, y, kp[(size_t)s * C_DIM]);

#pragma unroll 4
  for (int t = t0; t < t0 + 64; ++t) {
    y = fmaf(a, y, kp[(size_t)t * C_DIM]);
    float sq = y * y;
#pragma unroll
    for (int m = 1; m < 64; m <<= 1)
      sq += __shfl_xor(sq, m, 64);
    float nrm = sqrtf(sq) + 1e-10f;
    op[(size_t)t * HS] = y * (scale / nrm);
  }
}

// --------------------------------------------------------------- launcher
extern "C" void kernel_launch(void* const* d_in, const int* in_sizes, int n_in,
                              void* d_out, int out_size, void* d_ws, size_t ws_size,
                              hipStream_t stream) {
  const float* x      = (const float*)d_in[0];   // (8,2048,1024) f32
  const float* Wk     = (const float*)d_in[1];   // (1024,1024) f32
  const float* beta   = (const float*)d_in[2];   // (16) f32
  const float* kscale = (const float*)d_in[3];   // (16) f32
  const int*   spow   = (const int*)d_in[4];     // (1) int
  float* out = (float*)d_out;

  // workspace layout: x_f16 (32MB) | W_f16 (2MB) | k_f32 (64MB)  ~= 98MB
  f16* x_h = (f16*)d_ws;
  f16* W_h = x_h + (size_t)M_DIM * C_DIM;
  float* kbuf = (float*)(W_h + (size_t)C_DIM * C_DIM);

  cast_two<<<2048, 256, 0, stream>>>(x, x_h, (M_DIM * C_DIM) / 8,
                                     Wk, W_h, (C_DIM * C_DIM) / 8);
  gemm_bt_f16_8p<<<dim3((M_DIM / 256) * (C_DIM / 256)), 512, 0, stream>>>(x_h, W_h, kbuf);
  scan_norm<<<1024, 256, 0, stream>>>(kbuf, beta, kscale, spow, out);
}